// Round 2
// baseline (639.487 us; speedup 1.0000x reference)
//
#include <hip/hip_runtime.h>
#include <math.h>

// ---------------------------------------------------------------------------
// Phase 1: natural cubic spline coefficients (torchcubicspline convention),
// 3 channels: delay, coeff0, coeff1 (sigmoid-normalized). Single block.
// Uniform knots t_i = i/(nf-1):  M = hinv * T, T = tridiag(1,[2,4,...,4,2],1)
// k = T^{-1} (rhs * h).  Solved with Thomas algorithm in double.
// Coefficients stored per interval as (a, b, c, d) for a + b f + c f^2 + d f^3.
// ---------------------------------------------------------------------------
__global__ void spline_setup(const float* __restrict__ delay_in,  // [nf]
                             const float* __restrict__ raw,       // [nf][2]
                             double* __restrict__ coef,           // [3][nf-1][4]
                             int* __restrict__ minz,
                             int nf) {
    extern __shared__ double smem[];
    double* xch = smem;           // 3*nf channel values
    double* cp  = xch + 3 * nf;   // nf Thomas elimination coeffs (shared by channels)
    double* kk  = cp + nf;        // 3*nf solution (dp in-place then k)

    int tid = threadIdx.x;
    if (tid == 0) *minz = 0x7fffffff;

    for (int i = tid; i < nf; i += blockDim.x) {
        double s0 = 1.0 / (1.0 + exp(-(double)raw[2 * i + 0]));
        double s1 = 1.0 / (1.0 + exp(-(double)raw[2 * i + 1]));
        double ss = s0 + s1;
        xch[0 * nf + i] = (double)delay_in[i];
        xch[1 * nf + i] = s0 / ss;
        xch[2 * nf + i] = s1 / ss;
    }
    __syncthreads();

    if (tid == 0) {
        cp[0] = 0.5;  // upper/diag = 1/2
        for (int i = 1; i < nf; ++i) {
            double d = (i == nf - 1) ? 2.0 : 4.0;
            cp[i] = 1.0 / (d - cp[i - 1]);
        }
    }
    __syncthreads();

    if (tid < 3) {
        const double* x = xch + tid * nf;
        double* k = kk + tid * nf;
        double hinv = (double)(nf - 1);
        // forward sweep: dp[j] = (r[j] - dp[j-1]) * cp[j], r = rhs*h
        double prev = 0.0;
        for (int j = 0; j < nf; ++j) {
            double r = 0.0;
            if (j < nf - 1) r += 3.0 * hinv * (x[j + 1] - x[j]);
            if (j > 0)      r += 3.0 * hinv * (x[j] - x[j - 1]);
            double dp = (r - prev) * cp[j];
            k[j] = dp;
            prev = dp;
        }
        // back substitution
        for (int j = nf - 2; j >= 0; --j) k[j] = k[j] - cp[j] * k[j + 1];
    }
    __syncthreads();

    // per-interval coefficients, parallel over all threads
    int nint = nf - 1;
    double hinv = (double)(nf - 1);
    for (int w = tid; w < 3 * nint; w += blockDim.x) {
        int ch = w / nint;
        int i = w - ch * nint;
        const double* x = xch + ch * nf;
        const double* k = kk + ch * nf;
        double dx3 = 3.0 * (x[i + 1] - x[i]);
        double a = x[i];
        double b = k[i];
        double two_c   = (2.0 * dx3 * hinv - 4.0 * k[i] - 2.0 * k[i + 1]) * hinv;
        double three_d = (-2.0 * dx3 * hinv + 3.0 * (k[i] + k[i + 1])) * hinv * hinv;
        double* C = coef + (size_t)(ch * nint + i) * 4;
        C[0] = a;
        C[1] = b;
        C[2] = 0.5 * two_c;
        C[3] = three_d * (1.0 / 3.0);
    }
}

// ---------------------------------------------------------------------------
// Phase 2: per-sample spline evaluation -> z, g1, g2, g3, x. Parallel.
// ---------------------------------------------------------------------------
__global__ void eval_kernel(const double* __restrict__ coef,
                            const float* __restrict__ exc,
                            float4* __restrict__ gx,
                            int* __restrict__ zarr,
                            int* __restrict__ minz,
                            int n, int nf, int burst) {
    int j = blockIdx.x * blockDim.x + threadIdx.x;
    if (j >= n) return;

    double u = (double)j / (double)(n - 1);
    double nfm1 = (double)(nf - 1);
    int idx = (int)(u * nfm1);
    if (idx > nf - 2) idx = nf - 2;
    if (idx < 0) idx = 0;
    double tknot = (double)idx / nfm1;
    if (u < tknot && idx > 0) {
        idx--; tknot = (double)idx / nfm1;
    } else {
        double tnext = (double)(idx + 1) / nfm1;
        if (u >= tnext && idx < nf - 2) { idx++; tknot = tnext; }
    }
    double f = u - tknot;

    int nint = nf - 1;
    const double* C0 = coef + (size_t)(0 * nint + idx) * 4;
    const double* C1 = coef + (size_t)(1 * nint + idx) * 4;
    const double* C2 = coef + (size_t)(2 * nint + idx) * 4;
    double dly = C0[0] + f * (C0[1] + f * (C0[2] + f * C0[3]));
    double b1d = C1[0] + f * (C1[1] + f * (C1[2] + f * C1[3]));
    double b2d = C2[0] + f * (C2[1] + f * (C2[2] + f * C2[3]));

    double zf = floor(dly);
    int z = (int)zf;
    float alfa = (float)(dly - zf);
    float b1 = (float)b1d, b2 = (float)b2d;
    float g1 = b1 * (1.0f - alfa);
    float g2 = b1 * alfa + b2 * (1.0f - alfa);
    float g3 = b2 * alfa;
    float xx = (j < burst) ? exc[j] : 0.0f;

    gx[j] = make_float4(xx, g1, g2, g3);
    zarr[j] = z;

    // wave-level min, one atomic per wave
    int wmin = z;
    #pragma unroll
    for (int o = 32; o > 0; o >>= 1) wmin = min(wmin, __shfl_down(wmin, o, 64));
    if ((threadIdx.x & 63) == 0) atomicMin(minz, wmin);
}

// ---------------------------------------------------------------------------
// Phase 3: sequential chunked recurrence. Single block, 128 threads.
// Chunk size D = min(z)+1 (dependencies always reach >= D back).
// LDS circular buffer of 1024 samples; within a chunk, read slots (old
// samples) and write slots (current chunk) are disjoint because
// D + max_lookback < 1024  =>  single barrier per chunk.
// ---------------------------------------------------------------------------
__global__ void __launch_bounds__(128) scan_kernel(const float4* __restrict__ gx,
                                                   const int* __restrict__ zarr,
                                                   const int* __restrict__ minz,
                                                   float* __restrict__ y,
                                                   int n) {
    __shared__ float buf[1024];
    int tid = threadIdx.x;
    #pragma unroll
    for (int i = tid; i < 1024; i += 128) buf[i] = 0.0f;

    int D = *minz + 1;
    if (D > 128) D = 128;
    if (D < 1) D = 1;
    __syncthreads();

    // 2-deep register prefetch pipeline
    bool lane_on = (tid < D);
    int tA = tid;
    int tB = tid + D;
    float4 gA = (lane_on && tA < n) ? gx[tA] : make_float4(0.f, 0.f, 0.f, 0.f);
    int   zA = (lane_on && tA < n) ? zarr[tA] : 0;
    float4 gB = (lane_on && tB < n) ? gx[tB] : make_float4(0.f, 0.f, 0.f, 0.f);
    int   zB = (lane_on && tB < n) ? zarr[tB] : 0;

    for (int base = 0; base < n; base += D) {
        int tC = base + 2 * D + tid;
        bool ldC = lane_on && (tC < n);
        float4 gC = ldC ? gx[tC] : make_float4(0.f, 0.f, 0.f, 0.f);
        int   zC = ldC ? zarr[tC] : 0;

        int t = base + tid;
        bool act = lane_on && (t < n);
        float yv = 0.0f;
        if (act) {
            int s = t - zA;
            float y1 = buf[(s - 1) & 1023];
            float y2 = buf[(s - 2) & 1023];
            float y3 = buf[(s - 3) & 1023];
            yv = gA.x + gA.y * y1 + gA.z * y2 + gA.w * y3;
            buf[t & 1023] = yv;
            y[t] = yv;
        }
        __syncthreads();

        gA = gB; zA = zB;
        gB = gC; zB = zC;
    }
}

// ---------------------------------------------------------------------------
extern "C" void kernel_launch(void* const* d_in, const int* in_sizes, int n_in,
                              void* d_out, int out_size, void* d_ws, size_t ws_size,
                              hipStream_t stream) {
    const float* delay = (const float*)d_in[0];
    const float* raw   = (const float*)d_in[1];
    const float* exc   = (const float*)d_in[2];
    // d_in[3] is n_samples (device scalar); out_size equals n_samples.
    int nf = in_sizes[0];
    int burst = in_sizes[2];
    int n = out_size;

    char* ws = (char*)d_ws;
    size_t coefBytes = (size_t)3 * (nf - 1) * 4 * sizeof(double);
    size_t off = (coefBytes + 255) & ~(size_t)255;
    double* coef = (double*)ws;
    int* minz = (int*)(ws + off);
    off += 256;
    float4* gxa = (float4*)(ws + off);
    off += (size_t)n * sizeof(float4);
    int* zarr = (int*)(ws + off);

    size_t shmem = (size_t)(7 * nf) * sizeof(double);
    spline_setup<<<1, 64, shmem, stream>>>(delay, raw, coef, minz, nf);
    eval_kernel<<<(n + 255) / 256, 256, 0, stream>>>(coef, exc, gxa, zarr, minz, n, nf, burst);
    scan_kernel<<<1, 128, 0, stream>>>(gxa, zarr, minz, (float*)d_out, n);
}